// Round 7
// baseline (165.968 us; speedup 1.0000x reference)
//
#include <hip/hip_runtime.h>
#include <hip/hip_bf16.h>
#include <math.h>
#include <stdint.h>

// ---------------------------------------------------------------------------
// SCF_GRUCell: spatial binning of 400k neighbors -> segment mean (64 bins x 48)
// -> FC(48x3072)+ReLU -> scalar-gate GRU (rt is dead code in the reference).
//
// Round 7: R1-R6 falsified atomic/gather/LDS theories; the invariant is
// dur ~= FETCH/370GB/s with all pipes idle => per-wave MLP starvation (one
// load cluster in flight per iteration). Fix: register-batched loads — each
// wave issues 8 independent 1KB float4 loads (+binrow bytes) into register
// arrays BEFORE consuming any (8KB in flight/wave), then does the LDS ds_adds.
//
// ws float layout:
//   [0,48)                fsp
//   [64, 64+32*3136)      stage[32][3136] (3072 sums + 64 cnts)
//   [SLOT_OFF, +P*3200)   slots: per-block 3072 sums + 64 cnts
//   after slots:          binrow[n] bytes (bin per row; 64 = masked)
// ---------------------------------------------------------------------------

#define NBINS 64
#define ROWS 65
#define PAD 49
#define ENT 3136                 // slot: 3072 sums + 64 counts
#define SLOT 3200
#define GROUPS 32
#define FSP_OFF 0
#define STAGE_OFF 64
#define SLOT_OFF (STAGE_OFF + GROUPS * ENT)   // 100416
#define NBLK 256
#define UNROLL 8

__global__ __launch_bounds__(1024) void init_slots_kernel(
    float* __restrict__ slots, int total)
{
    int i = blockIdx.x * 1024 + threadIdx.x;
    int stride = gridDim.x * 1024;
    for (int k = i; k < total; k += stride) slots[k] = 0.0f;
}

__global__ __launch_bounds__(1024) void bin_kernel(
    const float2* __restrict__ loc_others,
    const float*  __restrict__ loc_agent,
    const int*    __restrict__ loc_other_index,
    uint8_t* __restrict__ binrow,
    int n)
{
    int i = blockIdx.x * 1024 + threadIdx.x;
    if (i >= n) return;
    const float ax = loc_agent[0];
    const float ay = loc_agent[1];
    float2 p = loc_others[i];
    float cx = p.x - ax;
    float cy = p.y - ay;
    float d = sqrtf(cx * cx + cy * cy);
    int bin = NBINS;  // dummy (masked)
    if (d >= 0.5f && d <= 40.0f) {
        float ac = acosf(fminf(fmaxf(cx / d, -1.0f), 1.0f));
        float theta = (cy < 0.0f) ? (6.283185307179586f - ac) : ac;
        float uf = floorf((d - 0.5f) / 4.9375f);           // RADIUS_STEP
        float vf = floorf(theta / 0.7853981633974483f);    // THETA_STEP
        int u = (int)fminf(fmaxf(uf, 0.0f), 7.0f);
        int v = (int)fminf(fmaxf(vf, 0.0f), 7.0f);
        bin = u * 8 + v;
    }
    binrow[loc_other_index[i]] = (uint8_t)bin;
}

__global__ __launch_bounds__(1024) void accum_kernel(
    const float4*  __restrict__ hflat,     // hiddens as float4[n*12]
    const uint8_t* __restrict__ binrow,    // [n]
    float* __restrict__ slots,             // [P][SLOT]
    int nf4, int P, int direct)
{
    __shared__ float s_sum[ROWS * PAD];    // 3185 floats (row 64 = dummy)
    for (int k = threadIdx.x; k < ROWS * PAD; k += 1024) s_sum[k] = 0.0f;
    __syncthreads();

    const int lane = threadIdx.x & 63;
    const int wave = (blockIdx.x * 1024 + threadIdx.x) >> 6;
    const int nwaves = (gridDim.x * 1024) >> 6;
    const int nbatch = (nf4 + 511) >> 9;   // 512 float4 per wave-batch

    for (int wb = wave; wb < nbatch; wb += nwaves) {
        int base = (wb << 9) + lane;

        // Phase 1: issue ALL loads into registers (independent, 8KB/wave in flight).
        float4 h[UNROLL];
        int bb[UNROLL];
        int ph[UNROLL];
#pragma unroll
        for (int i = 0; i < UNROLL; ++i) {
            int j = base + (i << 6);
            bool ok = j < nf4;
            unsigned jj = ok ? (unsigned)j : 0u;
            unsigned row = jj / 12u;
            ph[i] = ok ? (int)(jj - row * 12u) : -1;
            bb[i] = binrow[row];                // independent byte load
            h[i]  = hflat[jj];                  // independent 16B coalesced load
        }

        // Phase 2: consume into the shared histogram.
#pragma unroll
        for (int i = 0; i < UNROLL; ++i) {
            if (ph[i] < 0) continue;
            float* dst = s_sum + bb[i] * PAD + ph[i] * 4;
            unsafeAtomicAdd(dst + 0, h[i].x);
            unsafeAtomicAdd(dst + 1, h[i].y);
            unsafeAtomicAdd(dst + 2, h[i].z);
            unsafeAtomicAdd(dst + 3, h[i].w);
            if (ph[i] == 0)
                unsafeAtomicAdd(s_sum + bb[i] * PAD + 48, 1.0f);  // row count
        }
    }
    __syncthreads();

    // Epilogue: plain coalesced stores to this block's private slot.
    float* dst = slots + (size_t)(blockIdx.x % P) * SLOT;
    if (direct) {
        for (int k = threadIdx.x; k < 3072; k += 1024) {
            int b = k / 48;
            int j = k - b * 48;
            dst[k] = s_sum[b * PAD + j];
        }
        if (threadIdx.x < NBINS)
            dst[3072 + threadIdx.x] = s_sum[threadIdx.x * PAD + 48];
    } else {
        for (int k = threadIdx.x; k < 3072; k += 1024) {
            int b = k / 48;
            int j = k - b * 48;
            float v = s_sum[b * PAD + j];
            if (v != 0.0f) unsafeAtomicAdd(&dst[k], v);
        }
        if (threadIdx.x < NBINS) {
            float v = s_sum[threadIdx.x * PAD + 48];
            if (v != 0.0f) unsafeAtomicAdd(&dst[3072 + threadIdx.x], v);
        }
    }
}

__global__ __launch_bounds__(1024) void combine_kernel(
    const float* __restrict__ slots,   // [P][SLOT]
    float* __restrict__ stage,         // [GROUPS][ENT]
    int P)
{
    int t = blockIdx.x * 1024 + threadIdx.x;
    if (t >= GROUPS * ENT) return;
    unsigned g = (unsigned)t / (unsigned)ENT;
    unsigned k = (unsigned)t - g * ENT;
    int chunk = (P + GROUPS - 1) / GROUPS;
    int s0 = g * chunk;
    int s1 = s0 + chunk; if (s1 > P) s1 = P;
    float s = 0.0f;
#pragma unroll 4
    for (int b = s0; b < s1; ++b) s += slots[(size_t)b * SLOT + k];
    stage[t] = s;
}

__global__ __launch_bounds__(256) void fc_kernel(
    const float* __restrict__ W_fc,    // [48][3072]
    const float* __restrict__ b_fc,    // [48]
    const float* __restrict__ stage,   // [GROUPS][ENT]
    float* __restrict__ fsp)           // [48]
{
    __shared__ float s_cnt[NBINS];
    if (threadIdx.x < NBINS) {
        float c = 0.0f;
#pragma unroll
        for (int g = 0; g < GROUPS; ++g) c += stage[g * ENT + 3072 + threadIdx.x];
        s_cnt[threadIdx.x] = c;
    }
    __syncthreads();

    int r = blockIdx.x;
    const float* w = W_fc + (size_t)r * (NBINS * 48);
    float partial = 0.0f;
    for (int k = threadIdx.x; k < NBINS * 48; k += 256) {
        float s = 0.0f;
#pragma unroll
        for (int g = 0; g < GROUPS; ++g) s += stage[g * ENT + k];
        float c = s_cnt[k / 48];
        float sp = (c > 1.0f) ? (s / c) : s;
        partial += w[k] * sp;
    }
    for (int off = 32; off >= 1; off >>= 1) partial += __shfl_down(partial, off, 64);
    __shared__ float red[4];
    if ((threadIdx.x & 63) == 0) red[threadIdx.x >> 6] = partial;
    __syncthreads();
    if (threadIdx.x == 0) {
        float s = red[0] + red[1] + red[2] + red[3];
        fsp[r] = fmaxf(s + b_fc[r], 0.0f);
    }
}

__global__ void gru_kernel(
    const float* __restrict__ feature_img,  // [1,32,80,80]
    const float* __restrict__ loc_agent,    // [2]
    const float* __restrict__ f_vel,        // [16]
    const float* __restrict__ fsp,          // [48] (ws)
    const float* __restrict__ hidden,       // [48]
    const float* __restrict__ w_iz, const float* __restrict__ w_hz,
    const float* __restrict__ b_iz, const float* __restrict__ b_hz,
    const float* __restrict__ w_in, const float* __restrict__ w_hn,
    const float* __restrict__ b_in, const float* __restrict__ b_hn,
    float* __restrict__ out)                // [48]
{
    int l = threadIdx.x;  // one wave
    int u0 = 40 - (int)loc_agent[1];
    int v0 = (int)loc_agent[0];
    int pix = u0 * 80 + v0;

    float pz = 0.0f, pn = 0.0f;
    for (int e = l; e < 96; e += 64) {
        float x;
        if (e < 32)      x = feature_img[e * 6400 + pix];
        else if (e < 48) x = f_vel[e - 32];
        else             x = fsp[e - 48];
        pz += x * w_iz[e];
        pn += x * w_in[e];
    }
    if (l < 48) {
        float h = hidden[l];
        pz += h * w_hz[l];
        pn += h * w_hn[l];
    }
    for (int off = 32; off >= 1; off >>= 1) {
        pz += __shfl_xor(pz, off, 64);
        pn += __shfl_xor(pn, off, 64);
    }
    float zt = 1.0f / (1.0f + expf(-(pz + b_iz[0] + b_hz[0])));
    float nt = tanhf(pn + b_in[0] + b_hn[0]);
    if (l < 48) out[l] = (1.0f - zt) * nt + zt * hidden[l];
}

extern "C" void kernel_launch(void* const* d_in, const int* in_sizes, int n_in,
                              void* d_out, int out_size, void* d_ws, size_t ws_size,
                              hipStream_t stream) {
    const float* loc_agent       = (const float*)d_in[0];
    const float* loc_others      = (const float*)d_in[1];
    const int*   loc_other_index = (const int*)d_in[2];
    const float* feature_img     = (const float*)d_in[3];
    const float* f_vel           = (const float*)d_in[4];
    const float* hiddens         = (const float*)d_in[5];
    const float* hidden          = (const float*)d_in[6];
    const float* W_fc            = (const float*)d_in[7];
    const float* b_fc            = (const float*)d_in[8];
    // d_in[9..12] = weight_ir / weight_hr / bias_ir / bias_hr : dead code
    const float* w_iz            = (const float*)d_in[13];
    const float* w_hz            = (const float*)d_in[14];
    const float* b_iz            = (const float*)d_in[15];
    const float* b_hz            = (const float*)d_in[16];
    const float* w_in            = (const float*)d_in[17];
    const float* w_hn            = (const float*)d_in[18];
    const float* b_in            = (const float*)d_in[19];
    const float* b_hn            = (const float*)d_in[20];

    float* ws    = (float*)d_ws;
    float* fsp   = ws + FSP_OFF;
    float* stage = ws + STAGE_OFF;
    float* slots = ws + SLOT_OFF;
    float* out   = (float*)d_out;

    int n = in_sizes[2];            // 400000 neighbors
    int nf4 = n * 12;               // hiddens as float4 count
    long nwords = (n + 3) / 4;      // binrow u32 words

    long wfloats = (long)(ws_size / 4);
    long avail = (wfloats - SLOT_OFF - nwords) / SLOT;
    int P = (int)(avail < 1 ? 1 : (avail > NBLK ? NBLK : avail));
    int direct = (P == NBLK) ? 1 : 0;
    uint8_t* binrow = (uint8_t*)(ws + SLOT_OFF + (size_t)P * SLOT);

    if (!direct) {
        int total = P * SLOT;
        hipLaunchKernelGGL(init_slots_kernel, dim3((total + 1023) / 1024),
                           dim3(1024), 0, stream, slots, total);
    }
    hipLaunchKernelGGL(bin_kernel, dim3((n + 1023) / 1024), dim3(1024), 0, stream,
                       (const float2*)loc_others, loc_agent, loc_other_index,
                       binrow, n);
    hipLaunchKernelGGL(accum_kernel, dim3(NBLK), dim3(1024), 0, stream,
                       (const float4*)hiddens, binrow, slots, nf4, P, direct);
    hipLaunchKernelGGL(combine_kernel, dim3((GROUPS * ENT + 1023) / 1024), dim3(1024), 0, stream,
                       slots, stage, P);
    hipLaunchKernelGGL(fc_kernel, dim3(48), dim3(256), 0, stream,
                       W_fc, b_fc, stage, fsp);
    hipLaunchKernelGGL(gru_kernel, dim3(1), dim3(64), 0, stream,
                       feature_img, loc_agent, f_vel, fsp, hidden,
                       w_iz, w_hz, b_iz, b_hz, w_in, w_hn, b_in, b_hn, out);
}

// Round 8
// 114.006 us; speedup vs baseline: 1.4558x; 1.4558x over previous
//
#include <hip/hip_runtime.h>
#include <hip/hip_bf16.h>
#include <math.h>
#include <stdint.h>

// ---------------------------------------------------------------------------
// SCF_GRUCell round 8: ABLATION ROUND.
// Real path = best-known (R1 gather-accum, 73us) + store-only epilogue +
// parallel combine. Plus two pure-stream ablation kernels (measured
// separately by rocprof per-dispatch) to decide whether the ~400 GB/s pacing
// observed in R1-R7 is a platform/working-set cap or a kernel-shape artifact:
//   stream_a: 2048 blocks x 256 thr (6.3TB/s ubench geometry), 38.4 MB
//   stream_b:  256 blocks x 1024 thr (my kernels' geometry),   38.4 MB
//
// ws float layout:
//   [0,48)              fsp
//   [64,2112)           scrap (ablation live-store target, garbage)
//   [4096,104448)       stage[32][3136]
//   [104448,+P*3200)    slots (3072 sums + 64 cnts each)
// ---------------------------------------------------------------------------

#define NBINS 64
#define PAD 49
#define ENT 3136
#define SLOT 3200
#define GROUPS 32
#define FSP_OFF 0
#define SCRAP_OFF 64
#define STAGE_OFF 4096
#define SLOT_OFF (STAGE_OFF + GROUPS * ENT)   // 104448
#define NBLK 256

__global__ __launch_bounds__(1024) void init_slots_kernel(
    float* __restrict__ slots, int total)
{
    int i = blockIdx.x * 1024 + threadIdx.x;
    int stride = gridDim.x * 1024;
    for (int k = i; k < total; k += stride) slots[k] = 0.0f;
}

// R1's proven 73us kernel, epilogue -> private slot (plain stores when direct).
__global__ __launch_bounds__(1024) void accum_kernel(
    const float2* __restrict__ loc_others,
    const float*  __restrict__ loc_agent,
    const int*    __restrict__ loc_other_index,
    const float*  __restrict__ hiddens,
    float* __restrict__ slots,
    int n, int P, int direct)
{
    __shared__ float s_sum[NBINS * PAD];
    __shared__ float s_cnt[NBINS];
    for (int k = threadIdx.x; k < NBINS * PAD; k += 1024) s_sum[k] = 0.0f;
    if (threadIdx.x < NBINS) s_cnt[threadIdx.x] = 0.0f;
    __syncthreads();

    const float ax = loc_agent[0];
    const float ay = loc_agent[1];

    int t = blockIdx.x * 1024 + threadIdx.x;
    int stride = gridDim.x * 1024;
    for (int i = t; i < n; i += stride) {
        float2 p = loc_others[i];
        float cx = p.x - ax;
        float cy = p.y - ay;
        float d = sqrtf(cx * cx + cy * cy);
        if (d < 0.5f || d > 40.0f) continue;   // masked: row never touched

        float ac = acosf(fminf(fmaxf(cx / d, -1.0f), 1.0f));
        float theta = (cy < 0.0f) ? (6.283185307179586f - ac) : ac;
        float uf = floorf((d - 0.5f) / 4.9375f);           // RADIUS_STEP
        float vf = floorf(theta / 0.7853981633974483f);    // THETA_STEP
        int u = (int)fminf(fmaxf(uf, 0.0f), 7.0f);
        int v = (int)fminf(fmaxf(vf, 0.0f), 7.0f);
        int bin = u * 8 + v;

        int row = loc_other_index[i];
        const float4* hp = (const float4*)(hiddens + (size_t)row * 48);
        float* dst = s_sum + bin * PAD;
        unsafeAtomicAdd(&s_cnt[bin], 1.0f);
#pragma unroll
        for (int k = 0; k < 12; ++k) {
            float4 h = hp[k];
            unsafeAtomicAdd(dst + 4 * k + 0, h.x);
            unsafeAtomicAdd(dst + 4 * k + 1, h.y);
            unsafeAtomicAdd(dst + 4 * k + 2, h.z);
            unsafeAtomicAdd(dst + 4 * k + 3, h.w);
        }
    }
    __syncthreads();

    float* dst = slots + (size_t)(blockIdx.x % P) * SLOT;
    if (direct) {
        for (int k = threadIdx.x; k < 3072; k += 1024) {
            int b = k / 48;
            int j = k - b * 48;
            dst[k] = s_sum[b * PAD + j];
        }
        if (threadIdx.x < NBINS) dst[3072 + threadIdx.x] = s_cnt[threadIdx.x];
    } else {
        for (int k = threadIdx.x; k < 3072; k += 1024) {
            int b = k / 48;
            int j = k - b * 48;
            float v = s_sum[b * PAD + j];
            if (v != 0.0f) unsafeAtomicAdd(&dst[k], v);
        }
        if (threadIdx.x < NBINS) {
            float v = s_cnt[threadIdx.x];
            if (v != 0.0f) unsafeAtomicAdd(&dst[3072 + threadIdx.x], v);
        }
    }
}

__global__ __launch_bounds__(1024) void combine_kernel(
    const float* __restrict__ slots,   // [P][SLOT]
    float* __restrict__ stage,         // [GROUPS][ENT]
    int P)
{
    int t = blockIdx.x * 1024 + threadIdx.x;
    if (t >= GROUPS * ENT) return;
    unsigned g = (unsigned)t / (unsigned)ENT;
    unsigned k = (unsigned)t - g * ENT;
    int chunk = (P + GROUPS - 1) / GROUPS;
    int s0 = g * chunk;
    int s1 = s0 + chunk; if (s1 > P) s1 = P;
    float s = 0.0f;
#pragma unroll 4
    for (int b = s0; b < s1; ++b) s += slots[(size_t)b * SLOT + k];
    stage[t] = s;
}

__global__ __launch_bounds__(256) void fc_kernel(
    const float* __restrict__ W_fc,    // [48][3072]
    const float* __restrict__ b_fc,    // [48]
    const float* __restrict__ stage,   // [GROUPS][ENT]
    float* __restrict__ fsp)           // [48]
{
    __shared__ float s_cnt[NBINS];
    if (threadIdx.x < NBINS) {
        float c = 0.0f;
#pragma unroll
        for (int g = 0; g < GROUPS; ++g) c += stage[g * ENT + 3072 + threadIdx.x];
        s_cnt[threadIdx.x] = c;
    }
    __syncthreads();

    int r = blockIdx.x;
    const float* w = W_fc + (size_t)r * (NBINS * 48);
    float partial = 0.0f;
    for (int k = threadIdx.x; k < NBINS * 48; k += 256) {
        float s = 0.0f;
#pragma unroll
        for (int g = 0; g < GROUPS; ++g) s += stage[g * ENT + k];
        float c = s_cnt[k / 48];
        float sp = (c > 1.0f) ? (s / c) : s;
        partial += w[k] * sp;
    }
    for (int off = 32; off >= 1; off >>= 1) partial += __shfl_down(partial, off, 64);
    __shared__ float red[4];
    if ((threadIdx.x & 63) == 0) red[threadIdx.x >> 6] = partial;
    __syncthreads();
    if (threadIdx.x == 0) {
        float s = red[0] + red[1] + red[2] + red[3];
        fsp[r] = fmaxf(s + b_fc[r], 0.0f);
    }
}

__global__ void gru_kernel(
    const float* __restrict__ feature_img,
    const float* __restrict__ loc_agent,
    const float* __restrict__ f_vel,
    const float* __restrict__ fsp,
    const float* __restrict__ hidden,
    const float* __restrict__ w_iz, const float* __restrict__ w_hz,
    const float* __restrict__ b_iz, const float* __restrict__ b_hz,
    const float* __restrict__ w_in, const float* __restrict__ w_hn,
    const float* __restrict__ b_in, const float* __restrict__ b_hn,
    float* __restrict__ out)
{
    int l = threadIdx.x;  // one wave
    int u0 = 40 - (int)loc_agent[1];
    int v0 = (int)loc_agent[0];
    int pix = u0 * 80 + v0;

    float pz = 0.0f, pn = 0.0f;
    for (int e = l; e < 96; e += 64) {
        float x;
        if (e < 32)      x = feature_img[e * 6400 + pix];
        else if (e < 48) x = f_vel[e - 32];
        else             x = fsp[e - 48];
        pz += x * w_iz[e];
        pn += x * w_in[e];
    }
    if (l < 48) {
        float h = hidden[l];
        pz += h * w_hz[l];
        pn += h * w_hn[l];
    }
    for (int off = 32; off >= 1; off >>= 1) {
        pz += __shfl_xor(pz, off, 64);
        pn += __shfl_xor(pn, off, 64);
    }
    float zt = 1.0f / (1.0f + expf(-(pz + b_iz[0] + b_hz[0])));
    float nt = tanhf(pn + b_in[0] + b_hn[0]);
    if (l < 48) out[l] = (1.0f - zt) * nt + zt * hidden[l];
}

// --- Ablation kernels: pure float4 stream, register reduce, live store. ---
__global__ __launch_bounds__(256) void stream_a_kernel(
    const float4* __restrict__ h, float* __restrict__ scrap, int count, int offset)
{
    int t = blockIdx.x * 256 + threadIdx.x;
    int stride = gridDim.x * 256;
    float acc = 0.0f;
    for (int j = t; j < count; j += stride) {
        float4 v = h[offset + j];
        acc += v.x + v.y + v.z + v.w;
    }
    scrap[t & 2047] = acc;   // racy garbage; keeps loads live, never read
}

__global__ __launch_bounds__(1024) void stream_b_kernel(
    const float4* __restrict__ h, float* __restrict__ scrap, int count, int offset)
{
    int t = blockIdx.x * 1024 + threadIdx.x;
    int stride = gridDim.x * 1024;
    float acc = 0.0f;
    for (int j = t; j < count; j += stride) {
        float4 v = h[offset + j];
        acc += v.x + v.y + v.z + v.w;
    }
    scrap[t & 2047] = acc;
}

extern "C" void kernel_launch(void* const* d_in, const int* in_sizes, int n_in,
                              void* d_out, int out_size, void* d_ws, size_t ws_size,
                              hipStream_t stream) {
    const float* loc_agent       = (const float*)d_in[0];
    const float* loc_others      = (const float*)d_in[1];
    const int*   loc_other_index = (const int*)d_in[2];
    const float* feature_img     = (const float*)d_in[3];
    const float* f_vel           = (const float*)d_in[4];
    const float* hiddens         = (const float*)d_in[5];
    const float* hidden          = (const float*)d_in[6];
    const float* W_fc            = (const float*)d_in[7];
    const float* b_fc            = (const float*)d_in[8];
    // d_in[9..12] dead (rt gate)
    const float* w_iz            = (const float*)d_in[13];
    const float* w_hz            = (const float*)d_in[14];
    const float* b_iz            = (const float*)d_in[15];
    const float* b_hz            = (const float*)d_in[16];
    const float* w_in            = (const float*)d_in[17];
    const float* w_hn            = (const float*)d_in[18];
    const float* b_in            = (const float*)d_in[19];
    const float* b_hn            = (const float*)d_in[20];

    float* ws    = (float*)d_ws;
    float* fsp   = ws + FSP_OFF;
    float* scrap = ws + SCRAP_OFF;
    float* stage = ws + STAGE_OFF;
    float* slots = ws + SLOT_OFF;
    float* out   = (float*)d_out;

    int n = in_sizes[2];            // 400000
    int nf4 = n * 12;               // 4.8M float4
    int half = nf4 / 2;

    long wfloats = (long)(ws_size / 4);
    long avail = (wfloats - SLOT_OFF) / SLOT;
    int P = (int)(avail < 1 ? 1 : (avail > NBLK ? NBLK : avail));
    int direct = (P == NBLK) ? 1 : 0;

    if (!direct) {
        int total = P * SLOT;
        hipLaunchKernelGGL(init_slots_kernel, dim3((total + 1023) / 1024),
                           dim3(1024), 0, stream, slots, total);
    }
    hipLaunchKernelGGL(accum_kernel, dim3(NBLK), dim3(1024), 0, stream,
                       (const float2*)loc_others, loc_agent, loc_other_index,
                       hiddens, slots, n, P, direct);
    hipLaunchKernelGGL(combine_kernel, dim3((GROUPS * ENT + 1023) / 1024), dim3(1024), 0, stream,
                       slots, stage, P);
    hipLaunchKernelGGL(fc_kernel, dim3(48), dim3(256), 0, stream,
                       W_fc, b_fc, stage, fsp);
    hipLaunchKernelGGL(gru_kernel, dim3(1), dim3(64), 0, stream,
                       feature_img, loc_agent, f_vel, fsp, hidden,
                       w_iz, w_hz, b_iz, b_hz, w_in, w_hn, b_in, b_hn, out);
    // Ablations AFTER the real path so accum's L3 state matches R1 baseline.
    hipLaunchKernelGGL(stream_a_kernel, dim3(2048), dim3(256), 0, stream,
                       (const float4*)hiddens, scrap, half, 0);
    hipLaunchKernelGGL(stream_b_kernel, dim3(256), dim3(1024), 0, stream,
                       (const float4*)hiddens, scrap, half, half);
}